// Round 1
// baseline (125.747 us; speedup 1.0000x reference)
//
#include <hip/hip_runtime.h>
#include <hip/hip_bf16.h>

#define Bn 4
#define Sn 2048
#define Hn 768
#define NHn 12
#define Mn (Bn*Sn)
#define QKVN 2304

typedef unsigned short u16;
typedef unsigned int u32;
typedef __attribute__((ext_vector_type(8))) short short8;
typedef __attribute__((ext_vector_type(4))) float f32x4;

typedef __attribute__((address_space(1))) const u32 g_u32;
typedef __attribute__((address_space(3))) u32 l_u32;

__device__ __forceinline__ void gll16(const void* g, void* l) {
    __builtin_amdgcn_global_load_lds((g_u32*)g, (l_u32*)l, 16, 0, 0);
}

__device__ __forceinline__ u16 f2bf(float f) {
    u32 x = __float_as_uint(f);
    x += 0x7fffu + ((x >> 16) & 1u);   // round-to-nearest-even
    return (u16)(x >> 16);
}
__device__ __forceinline__ float bf2f(u16 u) {
    return __uint_as_float(((u32)u) << 16);
}

// ---------------- fp32 -> bf16 cast, float4 vectorized ----------------
__global__ __launch_bounds__(256) void cast_bf16_k(const float* __restrict__ src,
                                                   u16* __restrict__ dst, int n4) {
    int i = blockIdx.x * 256 + threadIdx.x;
    if (i >= n4) return;
    float4 v = ((const float4*)src)[i];
    ushort4 o;
    o.x = f2bf(v.x); o.y = f2bf(v.y); o.z = f2bf(v.z); o.w = f2bf(v.w);
    ((ushort4*)dst)[i] = o;
}

// ---------------- bf16 GEMM: C[M][N] = A[M][K] * B[N][K]^T ----------------
// 128x128 tile, BK=32, 4 waves (2x2), each wave 64x64 (4x4 frags of 16x16).
// LDS linear [row][32] with XOR swizzle applied via pre-swizzled global source
// (global_load_lds dest must be linear); reads apply the same XOR.
template <typename OUT>
__global__ __launch_bounds__(256) void gemm_bt(const u16* __restrict__ A,
                                               const u16* __restrict__ Bw,
                                               OUT* __restrict__ C, int N, int K) {
    __shared__ __align__(16) u16 As[128 * 32];
    __shared__ __align__(16) u16 Bs[128 * 32];
    const int t = threadIdx.x;
    const int wid = t >> 6, lane = t & 63;
    const int wr = wid >> 1, wc = wid & 1;
    const long m0 = (long)blockIdx.x * 128;
    const long n0 = (long)blockIdx.y * 128;
    const int lr = lane & 15, g = lane >> 4;

    f32x4 acc[4][4] = {};

    for (int kt = 0; kt < K; kt += 32) {
        #pragma unroll
        for (int ss = 0; ss < 2; ++ss) {
            int s = t + ss * 256;
            int row = s >> 2, gg = s & 3;
            int col8 = (gg ^ (row & 3)) * 8;   // inverse-swizzled source
            gll16(A + (m0 + row) * K + kt + col8, (char*)As + s * 16);
            gll16(Bw + (n0 + row) * K + kt + col8, (char*)Bs + s * 16);
        }
        __syncthreads();
        short8 af[4], bfr[4];
        #pragma unroll
        for (int mt = 0; mt < 4; ++mt) {
            int row = wr * 64 + mt * 16 + lr;
            af[mt] = *(const short8*)((const char*)As + row * 64 + ((g ^ (row & 3)) << 4));
        }
        #pragma unroll
        for (int nt = 0; nt < 4; ++nt) {
            int row = wc * 64 + nt * 16 + lr;
            bfr[nt] = *(const short8*)((const char*)Bs + row * 64 + ((g ^ (row & 3)) << 4));
        }
        #pragma unroll
        for (int mt = 0; mt < 4; ++mt)
            #pragma unroll
            for (int nt = 0; nt < 4; ++nt)
                acc[mt][nt] = __builtin_amdgcn_mfma_f32_16x16x32_bf16(af[mt], bfr[nt],
                                                                     acc[mt][nt], 0, 0, 0);
        __syncthreads();
    }

    #pragma unroll
    for (int mt = 0; mt < 4; ++mt)
        #pragma unroll
        for (int nt = 0; nt < 4; ++nt)
            #pragma unroll
            for (int r = 0; r < 4; ++r) {
                long row = m0 + wr * 64 + mt * 16 + g * 4 + r;
                long col = n0 + wc * 64 + nt * 16 + lr;
                float v = acc[mt][nt][r];
                if constexpr (sizeof(OUT) == 2) C[row * N + col] = (OUT)f2bf(v);
                else                            C[row * N + col] = v;
            }
}

// ---------------- RoPE in-place on q,k of qkv (bf16) ----------------
// one thread per (b,s,h,d2), d2 in [0,32); handles d2 and d2+32 for q and k.
__global__ __launch_bounds__(256) void rope_k(u16* __restrict__ qkv,
                                              const int* __restrict__ pos_ids) {
    int idx = blockIdx.x * 256 + threadIdx.x;   // Bn*Sn*NHn*32 exact
    int d2 = idx & 31;
    int h = (idx >> 5) % NHn;
    int bs = idx / (32 * NHn);
    int pos = pos_ids[bs];
    // inv_freq = 10000^(-d2/32) = 2^(-d2 * log2(10000)/32)
    float invf = exp2f((float)d2 * -0.4152410119f);
    float fr = (float)pos * invf;
    float sn, cs;
    sincosf(fr, &sn, &cs);
    size_t base = (size_t)bs * QKVN + (size_t)h * 64;
    #pragma unroll
    for (int tt = 0; tt < 2; ++tt) {
        u16* p = qkv + base + tt * 768;
        float x1 = bf2f(p[d2]), x2 = bf2f(p[d2 + 32]);
        p[d2]      = f2bf(x1 * cs - x2 * sn);
        p[d2 + 32] = f2bf(x2 * cs + x1 * sn);
    }
}

// ---------------- windowed attention ----------------
// block = (q-tile of 64, b*NH+h), 4 waves, each wave owns 16 q-rows.
// KV range = [q0-64, q0+127] (192 keys) covers window +-64 in one pass.
__global__ __launch_bounds__(256) void attn_k(const u16* __restrict__ qkv,
                                              u16* __restrict__ outb) {
    const int qt = blockIdx.x, bh = blockIdx.y;
    const int b = bh / NHn, h = bh % NHn;
    const int q0 = qt * 64, kv0 = q0 - 64;
    const int t = threadIdx.x, wid = t >> 6, lane = t & 63;
    const int lr = lane & 15, g = lane >> 4;

    __shared__ __align__(16) char smem[58368];
    u16* Qs = (u16*)smem;                // [64][64] swizzled, 8192 B
    u16* Ks = (u16*)(smem + 8192);       // [192][64] swizzled, 24576 B
    u16* Vt = (u16*)(smem + 32768);      // [64][200] transposed V, 25600 B
    // P region reuses [0, 25600) after QK^T (Qs+Ks dead by then)

    const size_t rowbase = (size_t)b * Sn;

    // stage Q (global_load_lds, linear LDS + inverse-swizzled source)
    #pragma unroll
    for (int ss = 0; ss < 2; ++ss) {
        int s = t + ss * 256;
        int row = s >> 3, gg = s & 7;
        int col8 = (gg ^ (row & 7)) * 8;
        gll16(qkv + (rowbase + q0 + row) * QKVN + h * 64 + col8, (char*)Qs + s * 16);
    }
    // stage K (rows clamped; mask covers OOB/garbage)
    #pragma unroll
    for (int ss = 0; ss < 6; ++ss) {
        int s = t + ss * 256;
        int row = s >> 3, gg = s & 7;
        int kk = kv0 + row;
        kk = kk < 0 ? 0 : (kk > Sn - 1 ? Sn - 1 : kk);
        int col8 = (gg ^ (row & 7)) * 8;
        gll16(qkv + (rowbase + kk) * QKVN + 768 + h * 64 + col8, (char*)Ks + s * 16);
    }
    // stage V transposed (reg-staged: coalesced 16B global read, 2B LDS scatter)
    #pragma unroll
    for (int ss = 0; ss < 6; ++ss) {
        int s = t + ss * 256;
        int krow = s >> 3, gg = s & 7;
        int kk = kv0 + krow;
        kk = kk < 0 ? 0 : (kk > Sn - 1 ? Sn - 1 : kk);
        short8 v = *(const short8*)(qkv + (rowbase + kk) * QKVN + 1536 + h * 64 + gg * 8);
        #pragma unroll
        for (int j = 0; j < 8; ++j) Vt[(gg * 8 + j) * 200 + krow] = (u16)v[j];
    }
    __syncthreads();

    // QK^T: 12 key-tiles x 2 d-halves = 24 MFMA per wave
    f32x4 sacc[12] = {};
    #pragma unroll
    for (int kk2 = 0; kk2 < 2; ++kk2) {
        int qrow = wid * 16 + lr;
        int slot = kk2 * 4 + g;
        short8 qf = *(const short8*)((const char*)Qs + qrow * 128 + ((slot ^ (qrow & 7)) << 4));
        #pragma unroll
        for (int tl = 0; tl < 12; ++tl) {
            int krow = tl * 16 + lr;
            short8 kf = *(const short8*)((const char*)Ks + krow * 128 + ((slot ^ (krow & 7)) << 4));
            sacc[tl] = __builtin_amdgcn_mfma_f32_16x16x32_bf16(qf, kf, sacc[tl], 0, 0, 0);
        }
    }

    // mask + softmax (row lives in a 16-lane group; width-16 shfl_xor reduce)
    float p[12][4];
    float lsum[4];
    #pragma unroll
    for (int r = 0; r < 4; ++r) {
        int qq = q0 + wid * 16 + g * 4 + r;
        float mx = -3.0e38f;
        #pragma unroll
        for (int tl = 0; tl < 12; ++tl) {
            int kq = kv0 + tl * 16 + lr;
            float sc = sacc[tl][r] * 0.125f;
            int dqk = qq - kq;
            bool valid = (kq >= 0) && (kq < Sn) && (dqk <= 64) && (dqk >= -64);
            sc = valid ? sc : -3.0e38f;
            p[tl][r] = sc;
            mx = fmaxf(mx, sc);
        }
        #pragma unroll
        for (int mk = 1; mk < 16; mk <<= 1) mx = fmaxf(mx, __shfl_xor(mx, mk, 16));
        float sum = 0.f;
        #pragma unroll
        for (int tl = 0; tl < 12; ++tl) {
            float e = __expf(p[tl][r] - mx);
            p[tl][r] = e;
            sum += e;
        }
        #pragma unroll
        for (int mk = 1; mk < 16; mk <<= 1) sum += __shfl_xor(sum, mk, 16);
        lsum[r] = sum;
    }

    __syncthreads();   // all waves done reading Qs/Ks before P overwrite

    // write P (bf16) to per-wave chunk, padded stride 200 elems (conflict-free)
    u16* Pw = (u16*)(smem + wid * 6400);
    #pragma unroll
    for (int tl = 0; tl < 12; ++tl)
        #pragma unroll
        for (int r = 0; r < 4; ++r)
            Pw[(g * 4 + r) * 200 + tl * 16 + lr] = f2bf(p[tl][r]);

    // PV: O(16x64) = P(16x192) * V(192x64); 6 k-steps x 4 d-tiles = 24 MFMA
    f32x4 oacc[4] = {};
    #pragma unroll
    for (int ks = 0; ks < 6; ++ks) {
        short8 pf = *(const short8*)((const char*)Pw + lr * 400 + (ks * 32 + g * 8) * 2);
        #pragma unroll
        for (int dt = 0; dt < 4; ++dt) {
            short8 vf = *(const short8*)((const char*)Vt + (dt * 16 + lr) * 400 + (ks * 32 + g * 8) * 2);
            oacc[dt] = __builtin_amdgcn_mfma_f32_16x16x32_bf16(pf, vf, oacc[dt], 0, 0, 0);
        }
    }

    // epilogue: divide by row sum, write bf16 [B*S][768] (head-major cols)
    #pragma unroll
    for (int dt = 0; dt < 4; ++dt)
        #pragma unroll
        for (int r = 0; r < 4; ++r) {
            int row = q0 + wid * 16 + g * 4 + r;
            float v = oacc[dt][r] / lsum[r];
            outb[(rowbase + row) * Hn + h * 64 + dt * 16 + lr] = f2bf(v);
        }
}

extern "C" void kernel_launch(void* const* d_in, const int* in_sizes, int n_in,
                              void* d_out, int out_size, void* d_ws, size_t ws_size,
                              hipStream_t stream) {
    const float* hs   = (const float*)d_in[0];
    const int*   pos  = (const int*)d_in[1];
    const float* wqkv = (const float*)d_in[2];
    const float* wo   = (const float*)d_in[3];
    float* out = (float*)d_out;
    char* ws = (char*)d_ws;

    // workspace layout (bytes)
    u16* hs_b   = (u16*)(ws);              // 8192*768*2   = 12,582,912
    u16* wqkv_b = (u16*)(ws + 12582912);   // 2304*768*2   =  3,538,944
    u16* wo_b   = (u16*)(ws + 16121856);   // 768*768*2    =  1,179,648
    u16* qkv    = (u16*)(ws + 17301504);   // 8192*2304*2  = 37,748,736
    u16* attn   = (u16*)(ws + 55050240);   // 8192*768*2   = 12,582,912  (end 67,633,152)

    cast_bf16_k<<<6144, 256, 0, stream>>>(hs, hs_b, 1572864);
    cast_bf16_k<<<1728, 256, 0, stream>>>(wqkv, wqkv_b, 442368);
    cast_bf16_k<<<576, 256, 0, stream>>>(wo, wo_b, 147456);

    // qkv[M][2304] = hs[M][768] @ Wqkv[2304][768]^T
    gemm_bt<u16><<<dim3(64, 18), 256, 0, stream>>>(hs_b, wqkv_b, qkv, 2304, 768);

    rope_k<<<12288, 256, 0, stream>>>(qkv, pos);

    attn_k<<<dim3(32, 48), 256, 0, stream>>>(qkv, attn);

    // out[M][768] = attn[M][768] @ Wo[768][768]^T  (fp32 output)
    gemm_bt<float><<<dim3(64, 6), 256, 0, stream>>>(attn, wo_b, out, 768, 768);
}